// Round 2
// baseline (680.137 us; speedup 1.0000x reference)
//
#include <hip/hip_runtime.h>
#include <math.h>

#define LN2F 0.69314718055994531f

typedef _Float16 v8hf __attribute__((ext_vector_type(8)));
typedef float    v4f  __attribute__((ext_vector_type(4)));

// fast shifted-softplus via v_exp_f32/v_log_f32 (~10 VALU instr vs ~50 libm).
__device__ __forceinline__ float ssp_fast(float x) {
    float e = __expf(-fabsf(x));
    return fmaxf(x, 0.f) + __logf(1.f + e) - LN2F;
}

// ---------------------------------------------------------------------------
// Prep: weights -> f16, MFMA-B-fragment order.
// ---------------------------------------------------------------------------
__global__ __launch_bounds__(256)
void prep_kernel(const float* __restrict__ w1, const float* __restrict__ w2,
                 const float* __restrict__ l1w, const float* __restrict__ l2w,
                 const float* __restrict__ lw,
                 _Float16* __restrict__ w1f, _Float16* __restrict__ w2f,
                 _Float16* __restrict__ l1f, _Float16* __restrict__ l2f,
                 _Float16* __restrict__ lwf)
{
    int idx = blockIdx.x * 256 + threadIdx.x;
    if (idx < 8192) {  // w1f
        int i = idx & 7, lane = (idx >> 3) & 63, ks = (idx >> 9) & 1, nt = idx >> 10;
        int r = nt * 16 + (lane & 15);
        int k = ks * 32 + (lane >> 4) * 8 + i;
        w1f[idx] = (k < 50) ? (_Float16)w1[r * 50 + k] : (_Float16)0.f;
        return;
    }
    int o = idx - 8192;
    if (o >= 4 * 16384) return;
    int which = o >> 14;
    int p = o & 16383;
    int i = p & 7, lane = (p >> 3) & 63, ks = (p >> 9) & 3, nt = p >> 11;
    int r = nt * 16 + (lane & 15);
    int k = ks * 32 + (lane >> 4) * 8 + i;
    const float* src = (which == 0) ? w2 : (which == 1) ? l1w : (which == 2) ? l2w : lw;
    _Float16* dst   = (which == 0) ? w2f : (which == 1) ? l1f : (which == 2) ? l2f : lwf;
    dst[p] = (_Float16)src[r * 128 + k];
}

// ---------------------------------------------------------------------------
// h = X @ W^T (no bias/act). Column-split across blockIdx.y for 2x blocks
// (625 blocks was ~2.4/CU -> latency-bound with no TLP).
// ---------------------------------------------------------------------------
__global__ __launch_bounds__(256)
void h_gemm_kernel(const float* __restrict__ X, const _Float16* __restrict__ Wf,
                   float* __restrict__ Y, int M)
{
    const int tid = threadIdx.x, lane = tid & 63, wv = tid >> 6;
    const int l15 = lane & 15, quad = lane >> 4;
    const int mb = blockIdx.x * 64 + wv * 16;
    const int nt0 = blockIdx.y * 4;

    const int mA = (mb + l15 < M) ? (mb + l15) : (M - 1);
    v8hf a[4];
    #pragma unroll
    for (int ks = 0; ks < 4; ++ks) {
        const float4* xp = (const float4*)&X[(size_t)mA * 128 + ks * 32 + quad * 8];
        float4 x0 = xp[0], x1 = xp[1];
        v8hf t = {(_Float16)x0.x, (_Float16)x0.y, (_Float16)x0.z, (_Float16)x0.w,
                  (_Float16)x1.x, (_Float16)x1.y, (_Float16)x1.z, (_Float16)x1.w};
        a[ks] = t;
    }
    #pragma unroll
    for (int nt = nt0; nt < nt0 + 4; ++nt) {
        v4f acc = {0.f, 0.f, 0.f, 0.f};
        #pragma unroll
        for (int ks = 0; ks < 4; ++ks) {
            const v8hf b = *(const v8hf*)&Wf[((nt * 4 + ks) * 64 + lane) * 8];
            acc = __builtin_amdgcn_mfma_f32_16x16x32_f16(a[ks], b, acc, 0, 0, 0);
        }
        const int col = nt * 16 + l15;
        #pragma unroll
        for (int r = 0; r < 4; ++r) {
            int row = mb + quad * 4 + r;
            if (row < M) Y[(size_t)row * 128 + col] = acc[r];
        }
    }
}

// ---------------------------------------------------------------------------
// Fused tail: out = ssp(agg @ l2^T + l2b) @ lw^T + lb.
// Stage-2 column-split across blockIdx.y (stage-1 recomputed; MFMA is ~5%
// utilized so duplication is free, parallelism doubles).
// ---------------------------------------------------------------------------
__global__ __launch_bounds__(256)
void fused_out_kernel(const float* __restrict__ agg, const _Float16* __restrict__ l2f,
                      const float* __restrict__ l2b, const _Float16* __restrict__ lwf,
                      const float* __restrict__ lb, float* __restrict__ out, int M)
{
    __shared__ __align__(16) _Float16 Sh[64 * 138];
    const int tid = threadIdx.x, lane = tid & 63, wv = tid >> 6;
    const int l15 = lane & 15, quad = lane >> 4;
    const int m0 = wv * 16;
    const int gbase = blockIdx.x * 64;
    const int nt0 = blockIdx.y * 4;

    const int mA = (gbase + m0 + l15 < M) ? (gbase + m0 + l15) : (M - 1);
    v8hf a[4];
    #pragma unroll
    for (int ks = 0; ks < 4; ++ks) {
        const float4* xp = (const float4*)&agg[(size_t)mA * 128 + ks * 32 + quad * 8];
        float4 x0 = xp[0], x1 = xp[1];
        v8hf t = {(_Float16)x0.x, (_Float16)x0.y, (_Float16)x0.z, (_Float16)x0.w,
                  (_Float16)x1.x, (_Float16)x1.y, (_Float16)x1.z, (_Float16)x1.w};
        a[ks] = t;
    }
    #pragma unroll
    for (int nt = 0; nt < 8; ++nt) {
        v4f acc = {0.f, 0.f, 0.f, 0.f};
        #pragma unroll
        for (int ks = 0; ks < 4; ++ks) {
            const v8hf b = *(const v8hf*)&l2f[((nt * 4 + ks) * 64 + lane) * 8];
            acc = __builtin_amdgcn_mfma_f32_16x16x32_f16(a[ks], b, acc, 0, 0, 0);
        }
        const float bj = l2b[nt * 16 + l15];
        #pragma unroll
        for (int r = 0; r < 4; ++r)
            Sh[(m0 + quad * 4 + r) * 138 + nt * 16 + l15] =
                (_Float16)ssp_fast(acc[r] + bj);
    }
    v8hf ua[4];
    #pragma unroll
    for (int ks = 0; ks < 4; ++ks)
        ua[ks] = *(const v8hf*)&Sh[(m0 + l15) * 138 + ks * 32 + quad * 8];

    #pragma unroll
    for (int nt = nt0; nt < nt0 + 4; ++nt) {
        v4f acc = {0.f, 0.f, 0.f, 0.f};
        #pragma unroll
        for (int ks = 0; ks < 4; ++ks) {
            const v8hf b = *(const v8hf*)&lwf[((nt * 4 + ks) * 64 + lane) * 8];
            acc = __builtin_amdgcn_mfma_f32_16x16x32_f16(ua[ks], b, acc, 0, 0, 0);
        }
        const int col = nt * 16 + l15;
        const float bj = lb[col];
        #pragma unroll
        for (int r = 0; r < 4; ++r) {
            int row = gbase + m0 + quad * 4 + r;
            if (row < M) out[(size_t)row * 128 + col] = acc[r] + bj;
        }
    }
}

// ---------------------------------------------------------------------------
// Edge kernel, PERMUTED order: block position p processes edge perm[p] and
// writes msg row at position p (dst-sorted). The downstream gather is then a
// pure sequential stream -- no perm indirection, no shuffles.
// attr reads become row-gathered (200B rows, ~1.3x overfetch) -- the trade
// that converts 328MB of random gather reads into a stream.
// launch_bounds (256,6): LDS 25.9KB allows exactly 6 blocks/CU (was 5).
// ---------------------------------------------------------------------------
__global__ __launch_bounds__(256, 6)
void edge_perm_kernel(const float* __restrict__ attr,  // E x 50
                      const float* __restrict__ ew,    // E
                      const int* __restrict__ srcI,
                      const int* __restrict__ perm,
                      const _Float16* __restrict__ w1f,
                      const _Float16* __restrict__ w2f,
                      const float* __restrict__ b1,
                      const float* __restrict__ b2,
                      const float* __restrict__ h,     // N x 128
                      float* __restrict__ msg,         // E x 128, CSR order
                      int E)
{
    __shared__ __align__(16) _Float16 Af[64 * 64];   // A-fragment-packed attr
    __shared__ __align__(16) _Float16 Uh[64 * 138];

    const int tid = threadIdx.x;
    const int e_base = blockIdx.x * 64;
    const int lane = tid & 63, wv = tid >> 6;
    const int m0 = wv * 16, l15 = lane & 15, quad = lane >> 4;

    // ---- per-lane edge metadata (16 lanes share p -> L1 broadcast) ----
    float cC[4]; const float* hrow[4]; bool val[4];
    #pragma unroll
    for (int r = 0; r < 4; ++r) {
        int p = e_base + m0 + quad * 4 + r;
        val[r] = p < E;
        int pe = perm[val[r] ? p : (E - 1)];
        cC[r] = 0.5f * (__cosf(ew[pe] * 0.31415926535897932f) + 1.f);
        hrow[r] = h + (size_t)srcI[pe] * 128;
    }

    // ---- stage attr -> LDS in A-fragment order (row via perm) ----
    for (int idx = tid; idx < 4096; idx += 256) {
        int r = idx >> 6, g = idx & 63;
        int e = e_base + r;
        int pe = perm[(e < E) ? e : (E - 1)];
        float v = (g < 50 && e < E) ? attr[(size_t)pe * 50 + g] : 0.f;
        Af[((((r >> 4) * 2 + (g >> 5)) * 64) + (((g & 31) >> 3) * 16) + (r & 15)) * 8
           + (g & 7)] = (_Float16)v;
    }
    __syncthreads();

    // ---- h-gather prefetch: latency hides behind both MFMA stages ----
    float hv[8][4];
    #pragma unroll
    for (int nt = 0; nt < 8; ++nt)
        #pragma unroll
        for (int r = 0; r < 4; ++r)
            hv[nt][r] = hrow[r][nt * 16 + l15];

    // ---- stage 1: u = ssp(attr @ W1^T + b1) -> Uh (wave-private rows) ----
    const v8hf a0 = *(const v8hf*)&Af[((wv * 2 + 0) * 64 + lane) * 8];
    const v8hf a1 = *(const v8hf*)&Af[((wv * 2 + 1) * 64 + lane) * 8];
    #pragma unroll
    for (int nt = 0; nt < 8; ++nt) {
        v4f acc = {0.f, 0.f, 0.f, 0.f};
        const v8hf bA = *(const v8hf*)&w1f[((nt * 2 + 0) * 64 + lane) * 8];
        const v8hf bB = *(const v8hf*)&w1f[((nt * 2 + 1) * 64 + lane) * 8];
        acc = __builtin_amdgcn_mfma_f32_16x16x32_f16(a0, bA, acc, 0, 0, 0);
        acc = __builtin_amdgcn_mfma_f32_16x16x32_f16(a1, bB, acc, 0, 0, 0);
        const float bj = b1[nt * 16 + l15];
        #pragma unroll
        for (int r = 0; r < 4; ++r)
            Uh[(m0 + quad * 4 + r) * 138 + nt * 16 + l15] =
                (_Float16)ssp_fast(acc[r] + bj);
    }

    // ---- stage 2 + D-layout epilogue: plain stores at block-linear rows ----
    v8hf ua[4];
    #pragma unroll
    for (int ks = 0; ks < 4; ++ks)
        ua[ks] = *(const v8hf*)&Uh[(m0 + l15) * 138 + ks * 32 + quad * 8];

    #pragma unroll
    for (int nt = 0; nt < 8; ++nt) {
        v4f acc = {0.f, 0.f, 0.f, 0.f};
        #pragma unroll
        for (int ks = 0; ks < 4; ++ks) {
            const v8hf b = *(const v8hf*)&w2f[((nt * 4 + ks) * 64 + lane) * 8];
            acc = __builtin_amdgcn_mfma_f32_16x16x32_f16(ua[ks], b, acc, 0, 0, 0);
        }
        const int col = nt * 16 + l15;
        const float bj = b2[col];
        #pragma unroll
        for (int r = 0; r < 4; ++r) {
            if (val[r]) {
                int p = e_base + m0 + quad * 4 + r;
                msg[(size_t)p * 128 + col] = (acc[r] + bj) * cC[r] * hv[nt][r];
            }
        }
    }
}

// ---------------------------------------------------------------------------
// Legacy atomic-scatter edge kernel (fallback when workspace < msg buffer).
// ---------------------------------------------------------------------------
__global__ __launch_bounds__(256, 5)
void edge_legacy_kernel(const float* __restrict__ attr, const float* __restrict__ ew,
                        const int* __restrict__ srcI, const int* __restrict__ dstI,
                        const _Float16* __restrict__ w1f, const _Float16* __restrict__ w2f,
                        const float* __restrict__ b1, const float* __restrict__ b2,
                        const float* __restrict__ h, float* __restrict__ agg, int E)
{
    __shared__ __align__(16) _Float16 Af[64 * 64];
    __shared__ __align__(16) _Float16 Uh[64 * 138];
    const int tid = threadIdx.x;
    const int e_base = blockIdx.x * 64;
    const int lane = tid & 63, wv = tid >> 6;
    const int m0 = wv * 16, l15 = lane & 15, quad = lane >> 4;

    float cC[4]; const float* hrow[4]; float* arow[4]; bool val[4];
    #pragma unroll
    for (int r = 0; r < 4; ++r) {
        int eg = e_base + m0 + quad * 4 + r;
        val[r] = eg < E;
        int e = val[r] ? eg : (E - 1);
        cC[r] = 0.5f * (__cosf(ew[e] * 0.31415926535897932f) + 1.f);
        hrow[r] = h + (size_t)srcI[e] * 128;
        arow[r] = agg + (size_t)dstI[e] * 128;
    }
    for (int idx = tid; idx < 4096; idx += 256) {
        int r = idx >> 6, g = idx & 63;
        int e = e_base + r;
        float v = (g < 50 && e < E) ? attr[(size_t)e * 50 + g] : 0.f;
        Af[((((r >> 4) * 2 + (g >> 5)) * 64) + (((g & 31) >> 3) * 16) + (r & 15)) * 8
           + (g & 7)] = (_Float16)v;
    }
    __syncthreads();
    float hv[8][4];
    #pragma unroll
    for (int nt = 0; nt < 8; ++nt)
        #pragma unroll
        for (int r = 0; r < 4; ++r)
            hv[nt][r] = hrow[r][nt * 16 + l15];

    const v8hf a0 = *(const v8hf*)&Af[((wv * 2 + 0) * 64 + lane) * 8];
    const v8hf a1 = *(const v8hf*)&Af[((wv * 2 + 1) * 64 + lane) * 8];
    #pragma unroll
    for (int nt = 0; nt < 8; ++nt) {
        v4f acc = {0.f, 0.f, 0.f, 0.f};
        const v8hf bA = *(const v8hf*)&w1f[((nt * 2 + 0) * 64 + lane) * 8];
        const v8hf bB = *(const v8hf*)&w1f[((nt * 2 + 1) * 64 + lane) * 8];
        acc = __builtin_amdgcn_mfma_f32_16x16x32_f16(a0, bA, acc, 0, 0, 0);
        acc = __builtin_amdgcn_mfma_f32_16x16x32_f16(a1, bB, acc, 0, 0, 0);
        const float bj = b1[nt * 16 + l15];
        #pragma unroll
        for (int r = 0; r < 4; ++r)
            Uh[(m0 + quad * 4 + r) * 138 + nt * 16 + l15] =
                (_Float16)ssp_fast(acc[r] + bj);
    }
    v8hf ua[4];
    #pragma unroll
    for (int ks = 0; ks < 4; ++ks)
        ua[ks] = *(const v8hf*)&Uh[(m0 + l15) * 138 + ks * 32 + quad * 8];
    #pragma unroll
    for (int nt = 0; nt < 8; ++nt) {
        v4f acc = {0.f, 0.f, 0.f, 0.f};
        #pragma unroll
        for (int ks = 0; ks < 4; ++ks) {
            const v8hf b = *(const v8hf*)&w2f[((nt * 4 + ks) * 64 + lane) * 8];
            acc = __builtin_amdgcn_mfma_f32_16x16x32_f16(ua[ks], b, acc, 0, 0, 0);
        }
        const int col = nt * 16 + l15;
        const float bj = b2[col];
        #pragma unroll
        for (int r = 0; r < 4; ++r)
            if (val[r]) atomicAdd(&arow[r][col], (acc[r] + bj) * cC[r] * hv[nt][r]);
    }
}

// ---------------------------------------------------------------------------
// CSR build: histogram of dst -> exclusive scan -> scatter edge ids.
// ---------------------------------------------------------------------------
__global__ __launch_bounds__(256)
void hist_kernel(const int* __restrict__ dst, int* __restrict__ counts, int E)
{
    int i = blockIdx.x * 256 + threadIdx.x;
    const int stride = gridDim.x * 256;
    for (; i < E; i += stride) atomicAdd(&counts[dst[i]], 1);
}

__global__ __launch_bounds__(256)
void scan1_kernel(int* __restrict__ data, int* __restrict__ bsum, int N)
{
    __shared__ int wsum[4];
    const int t = threadIdx.x, lane = t & 63, wv = t >> 6;
    const int base = blockIdx.x * 1024 + t * 4;
    int v0 = 0, v1 = 0, v2 = 0, v3 = 0;
    if (base + 0 < N) v0 = data[base + 0];
    if (base + 1 < N) v1 = data[base + 1];
    if (base + 2 < N) v2 = data[base + 2];
    if (base + 3 < N) v3 = data[base + 3];
    const int s = v0 + v1 + v2 + v3;
    int sc = s;
    #pragma unroll
    for (int d = 1; d < 64; d <<= 1) {
        int o = __shfl_up(sc, d);
        if (lane >= d) sc += o;
    }
    if (lane == 63) wsum[wv] = sc;
    __syncthreads();
    int wo = 0;
    for (int j = 0; j < wv; ++j) wo += wsum[j];
    int run = wo + (sc - s);
    if (base + 0 < N) data[base + 0] = run; run += v0;
    if (base + 1 < N) data[base + 1] = run; run += v1;
    if (base + 2 < N) data[base + 2] = run; run += v2;
    if (base + 3 < N) data[base + 3] = run; run += v3;
    if (t == 255) bsum[blockIdx.x] = wo + sc;
}

__global__ __launch_bounds__(256)
void scan2_kernel(int* __restrict__ offs, const int* __restrict__ bsum,
                  int* __restrict__ cur, int N, int E)
{
    int add = 0;
    for (int j = 0; j < (int)blockIdx.x; ++j) add += bsum[j];
    const int base = blockIdx.x * 1024 + threadIdx.x * 4;
    #pragma unroll
    for (int r = 0; r < 4; ++r) {
        int i = base + r;
        if (i < N) { int o = offs[i] + add; offs[i] = o; cur[i] = o; }
    }
    if (blockIdx.x == 0 && threadIdx.x == 0) offs[N] = E;
}

__global__ __launch_bounds__(256)
void scatter_kernel(const int* __restrict__ dst, int* __restrict__ cur,
                    int* __restrict__ perm, int E)
{
    int i = blockIdx.x * 256 + threadIdx.x;
    const int stride = gridDim.x * 256;
    for (; i < E; i += stride) {
        int p = atomicAdd(&cur[dst[i]], 1);
        perm[p] = i;
    }
}

// ---------------------------------------------------------------------------
// Gather, sequential: msg is in CSR order, so node n's rows are contiguous.
// One wave per node, lane owns 2 cols (512B/row across the wave). Pure
// sequential stream, 4-deep unrolled for MLP. Writes every row -> no memset.
// ---------------------------------------------------------------------------
__global__ __launch_bounds__(256)
void gather_kernel(const float* __restrict__ msg, const int* __restrict__ offs,
                   float* __restrict__ agg, int N)
{
    const int lane = threadIdx.x & 63, wv = threadIdx.x >> 6;
    const int n = blockIdx.x * 4 + wv;
    if (n >= N) return;
    const int s = offs[n], e = offs[n + 1];
    const float* p = msg + (size_t)s * 128 + lane * 2;
    float ax0 = 0.f, ay0 = 0.f, ax1 = 0.f, ay1 = 0.f;
    float ax2 = 0.f, ay2 = 0.f, ax3 = 0.f, ay3 = 0.f;
    int k = s;
    for (; k + 3 < e; k += 4) {
        float2 m0 = *(const float2*)(p);
        float2 m1 = *(const float2*)(p + 128);
        float2 m2 = *(const float2*)(p + 256);
        float2 m3 = *(const float2*)(p + 384);
        p += 512;
        ax0 += m0.x; ay0 += m0.y; ax1 += m1.x; ay1 += m1.y;
        ax2 += m2.x; ay2 += m2.y; ax3 += m3.x; ay3 += m3.y;
    }
    for (; k < e; ++k) {
        float2 m = *(const float2*)p; p += 128;
        ax0 += m.x; ay0 += m.y;
    }
    float2 o;
    o.x = (ax0 + ax1) + (ax2 + ax3);
    o.y = (ay0 + ay1) + (ay2 + ay3);
    *(float2*)&agg[(size_t)n * 128 + lane * 2] = o;
}

extern "C" void kernel_launch(void* const* d_in, const int* in_sizes, int n_in,
                              void* d_out, int out_size, void* d_ws, size_t ws_size,
                              hipStream_t stream)
{
    const float* x   = (const float*)d_in[0];
    const int*   ei  = (const int*)  d_in[1];
    const float* ew  = (const float*)d_in[2];
    const float* ea  = (const float*)d_in[3];
    const float* w1  = (const float*)d_in[4];
    const float* b1  = (const float*)d_in[5];
    const float* w2  = (const float*)d_in[6];
    const float* b2  = (const float*)d_in[7];
    const float* l1w = (const float*)d_in[8];
    const float* l2w = (const float*)d_in[9];
    const float* l2b = (const float*)d_in[10];
    const float* lw  = (const float*)d_in[11];
    const float* lb  = (const float*)d_in[12];

    const int N = in_sizes[0] / 128;   // 40000
    const int E = in_sizes[2];         // 640000
    const int NB = (N + 1023) / 1024;

    char* base = (char*)d_ws;
    size_t off = 0;
    auto take = [&](size_t bytes) -> char* {
        char* r = base + off;
        off = (off + bytes + 255) & ~(size_t)255;
        return r;
    };
    float*    hbuf = (float*)   take((size_t)N * 128 * 4);
    float*    agg  = (float*)   take((size_t)N * 128 * 4);
    _Float16* w1f  = (_Float16*)take(8192 * 2);
    _Float16* w2f  = (_Float16*)take(16384 * 2);
    _Float16* l1f  = (_Float16*)take(16384 * 2);
    _Float16* l2f  = (_Float16*)take(16384 * 2);
    _Float16* lwf  = (_Float16*)take(16384 * 2);
    int*      offs = (int*)     take((size_t)(N + 1) * 4);
    int*      cur  = (int*)     take((size_t)N * 4);
    int*      bsum = (int*)     take((size_t)NB * 4);
    int*      perm = (int*)     take((size_t)E * 4);
    const size_t base_bytes = off;

    const bool fits = ws_size >= base_bytes + (size_t)E * 128 * 4;
    float* msg = (float*)(base + off);

    const int nb = (N + 63) / 64;
    const int eb = (E + 63) / 64;
    const int tb = (E + 255) / 256;

    prep_kernel<<<288, 256, 0, stream>>>(w1, w2, l1w, l2w, lw,
                                         w1f, w2f, l1f, l2f, lwf);
    h_gemm_kernel<<<dim3(nb, 2), 256, 0, stream>>>(x, l1f, hbuf, N);

    if (!fits) {
        hipMemsetAsync(agg, 0, (size_t)N * 128 * sizeof(float), stream);
        edge_legacy_kernel<<<eb, 256, 0, stream>>>(ea, ew, ei, ei + E, w1f, w2f,
                                                   b1, b2, hbuf, agg, E);
    } else {
        hipMemsetAsync(offs, 0, (size_t)(N + 1) * sizeof(int), stream);
        hist_kernel<<<tb, 256, 0, stream>>>(ei + E, offs, E);
        scan1_kernel<<<NB, 256, 0, stream>>>(offs, bsum, N);
        scan2_kernel<<<NB, 256, 0, stream>>>(offs, bsum, cur, N, E);
        scatter_kernel<<<tb, 256, 0, stream>>>(ei + E, cur, perm, E);
        edge_perm_kernel<<<eb, 256, 0, stream>>>(ea, ew, ei, perm, w1f, w2f,
                                                 b1, b2, hbuf, msg, E);
        gather_kernel<<<(N + 3) / 4, 256, 0, stream>>>(msg, offs, agg, N);
    }
    fused_out_kernel<<<dim3(nb, 2), 256, 0, stream>>>(agg, l2f, l2b, lwf, lb,
                                                      (float*)d_out, N);
}

// Round 3
// 543.369 us; speedup vs baseline: 1.2517x; 1.2517x over previous
//
#include <hip/hip_runtime.h>
#include <math.h>

#define LN2F 0.69314718055994531f

typedef _Float16 v8hf __attribute__((ext_vector_type(8)));
typedef float    v4f  __attribute__((ext_vector_type(4)));

// fast shifted-softplus via v_exp_f32/v_log_f32 (~10 VALU instr vs ~50 libm).
__device__ __forceinline__ float ssp_fast(float x) {
    float e = __expf(-fabsf(x));
    return fmaxf(x, 0.f) + __logf(1.f + e) - LN2F;
}

// ---------------------------------------------------------------------------
// Prep: weights -> f16, MFMA-B-fragment order.
// ---------------------------------------------------------------------------
__global__ __launch_bounds__(256)
void prep_kernel(const float* __restrict__ w1, const float* __restrict__ w2,
                 const float* __restrict__ l1w, const float* __restrict__ l2w,
                 const float* __restrict__ lw,
                 _Float16* __restrict__ w1f, _Float16* __restrict__ w2f,
                 _Float16* __restrict__ l1f, _Float16* __restrict__ l2f,
                 _Float16* __restrict__ lwf)
{
    int idx = blockIdx.x * 256 + threadIdx.x;
    if (idx < 8192) {  // w1f
        int i = idx & 7, lane = (idx >> 3) & 63, ks = (idx >> 9) & 1, nt = idx >> 10;
        int r = nt * 16 + (lane & 15);
        int k = ks * 32 + (lane >> 4) * 8 + i;
        w1f[idx] = (k < 50) ? (_Float16)w1[r * 50 + k] : (_Float16)0.f;
        return;
    }
    int o = idx - 8192;
    if (o >= 4 * 16384) return;
    int which = o >> 14;
    int p = o & 16383;
    int i = p & 7, lane = (p >> 3) & 63, ks = (p >> 9) & 3, nt = p >> 11;
    int r = nt * 16 + (lane & 15);
    int k = ks * 32 + (lane >> 4) * 8 + i;
    const float* src = (which == 0) ? w2 : (which == 1) ? l1w : (which == 2) ? l2w : lw;
    _Float16* dst   = (which == 0) ? w2f : (which == 1) ? l1f : (which == 2) ? l2f : lwf;
    dst[p] = (_Float16)src[r * 128 + k];
}

// ---------------------------------------------------------------------------
// h = X @ W^T (no bias/act). Column-split across blockIdx.y for 2x blocks.
// ---------------------------------------------------------------------------
__global__ __launch_bounds__(256)
void h_gemm_kernel(const float* __restrict__ X, const _Float16* __restrict__ Wf,
                   float* __restrict__ Y, int M)
{
    const int tid = threadIdx.x, lane = tid & 63, wv = tid >> 6;
    const int l15 = lane & 15, quad = lane >> 4;
    const int mb = blockIdx.x * 64 + wv * 16;
    const int nt0 = blockIdx.y * 4;

    const int mA = (mb + l15 < M) ? (mb + l15) : (M - 1);
    v8hf a[4];
    #pragma unroll
    for (int ks = 0; ks < 4; ++ks) {
        const float4* xp = (const float4*)&X[(size_t)mA * 128 + ks * 32 + quad * 8];
        float4 x0 = xp[0], x1 = xp[1];
        v8hf t = {(_Float16)x0.x, (_Float16)x0.y, (_Float16)x0.z, (_Float16)x0.w,
                  (_Float16)x1.x, (_Float16)x1.y, (_Float16)x1.z, (_Float16)x1.w};
        a[ks] = t;
    }
    #pragma unroll
    for (int nt = nt0; nt < nt0 + 4; ++nt) {
        v4f acc = {0.f, 0.f, 0.f, 0.f};
        #pragma unroll
        for (int ks = 0; ks < 4; ++ks) {
            const v8hf b = *(const v8hf*)&Wf[((nt * 4 + ks) * 64 + lane) * 8];
            acc = __builtin_amdgcn_mfma_f32_16x16x32_f16(a[ks], b, acc, 0, 0, 0);
        }
        const int col = nt * 16 + l15;
        #pragma unroll
        for (int r = 0; r < 4; ++r) {
            int row = mb + quad * 4 + r;
            if (row < M) Y[(size_t)row * 128 + col] = acc[r];
        }
    }
}

// ---------------------------------------------------------------------------
// Fused tail: out = ssp(agg @ l2^T + l2b) @ lw^T + lb.
// Stage-2 column-split across blockIdx.y (stage-1 recomputed, MFMA is cheap).
// ---------------------------------------------------------------------------
__global__ __launch_bounds__(256)
void fused_out_kernel(const float* __restrict__ agg, const _Float16* __restrict__ l2f,
                      const float* __restrict__ l2b, const _Float16* __restrict__ lwf,
                      const float* __restrict__ lb, float* __restrict__ out, int M)
{
    __shared__ __align__(16) _Float16 Sh[64 * 138];
    const int tid = threadIdx.x, lane = tid & 63, wv = tid >> 6;
    const int l15 = lane & 15, quad = lane >> 4;
    const int m0 = wv * 16;
    const int gbase = blockIdx.x * 64;
    const int nt0 = blockIdx.y * 4;

    const int mA = (gbase + m0 + l15 < M) ? (gbase + m0 + l15) : (M - 1);
    v8hf a[4];
    #pragma unroll
    for (int ks = 0; ks < 4; ++ks) {
        const float4* xp = (const float4*)&agg[(size_t)mA * 128 + ks * 32 + quad * 8];
        float4 x0 = xp[0], x1 = xp[1];
        v8hf t = {(_Float16)x0.x, (_Float16)x0.y, (_Float16)x0.z, (_Float16)x0.w,
                  (_Float16)x1.x, (_Float16)x1.y, (_Float16)x1.z, (_Float16)x1.w};
        a[ks] = t;
    }
    #pragma unroll
    for (int nt = 0; nt < 8; ++nt) {
        v4f acc = {0.f, 0.f, 0.f, 0.f};
        #pragma unroll
        for (int ks = 0; ks < 4; ++ks) {
            const v8hf b = *(const v8hf*)&l2f[((nt * 4 + ks) * 64 + lane) * 8];
            acc = __builtin_amdgcn_mfma_f32_16x16x32_f16(a[ks], b, acc, 0, 0, 0);
        }
        const float bj = l2b[nt * 16 + l15];
        #pragma unroll
        for (int r = 0; r < 4; ++r)
            Sh[(m0 + quad * 4 + r) * 138 + nt * 16 + l15] =
                (_Float16)ssp_fast(acc[r] + bj);
    }
    v8hf ua[4];
    #pragma unroll
    for (int ks = 0; ks < 4; ++ks)
        ua[ks] = *(const v8hf*)&Sh[(m0 + l15) * 138 + ks * 32 + quad * 8];

    #pragma unroll
    for (int nt = nt0; nt < nt0 + 4; ++nt) {
        v4f acc = {0.f, 0.f, 0.f, 0.f};
        #pragma unroll
        for (int ks = 0; ks < 4; ++ks) {
            const v8hf b = *(const v8hf*)&lwf[((nt * 4 + ks) * 64 + lane) * 8];
            acc = __builtin_amdgcn_mfma_f32_16x16x32_f16(ua[ks], b, acc, 0, 0, 0);
        }
        const int col = nt * 16 + l15;
        const float bj = lb[col];
        #pragma unroll
        for (int r = 0; r < 4; ++r) {
            int row = gbase + m0 + quad * 4 + r;
            if (row < M) out[(size_t)row * 128 + col] = acc[r] + bj;
        }
    }
}

// ---------------------------------------------------------------------------
// Edge kernel v3: one-pass atomic scatter, BARRIER-FREE.
//   - A-fragments loaded DIRECTLY from attr (lane reads its own 32B slice of
//     its edge row as guarded float2s; rows are 200B pitch, 8B aligned).
//     Deletes the Af LDS buffer, the 16-load staging loop, and the only
//     __syncthreads. Uh is strictly wave-private (same wave writes & reads)
//     -> no race without barriers (the old r4 divergence raced on shared Af).
//   - LDS 26.1 -> 17.6 KB; launch_bounds(256,7) -> 7 blocks/CU (~87% occ,
//     was 65%). VGPR cap 73.
//   - h[src] prefetched to registers up front; atomics remain fire-and-forget
//     64B-coalesced per (r,nt) group (r1 evidence: atomic pipe was NOT the
//     cap -- issue latency was).
// ---------------------------------------------------------------------------
__global__ __launch_bounds__(256, 7)
void edge_kernel(const float* __restrict__ attr,  // E x 50
                 const float* __restrict__ ew,    // E
                 const int* __restrict__ srcI,
                 const int* __restrict__ dstI,
                 const _Float16* __restrict__ w1f,
                 const _Float16* __restrict__ w2f,
                 const float* __restrict__ b1,
                 const float* __restrict__ b2,
                 const float* __restrict__ h,     // N x 128
                 float* __restrict__ agg,         // N x 128 (zeroed)
                 int E)
{
    __shared__ __align__(16) _Float16 Uh[64 * 138];

    const int tid = threadIdx.x;
    const int e_base = blockIdx.x * 64;
    const int lane = tid & 63, wv = tid >> 6;
    const int m0 = wv * 16, l15 = lane & 15, quad = lane >> 4;

    // ---- per-lane edge metadata (16-lane groups share -> L1 broadcast) ----
    float cC[4]; const float* hrow[4]; float* arow[4]; bool val[4];
    #pragma unroll
    for (int r = 0; r < 4; ++r) {
        int eg = e_base + m0 + quad * 4 + r;
        val[r] = eg < E;
        int e = val[r] ? eg : (E - 1);
        cC[r] = 0.5f * (__cosf(ew[e] * 0.31415926535897932f) + 1.f);
        hrow[r] = h + (size_t)srcI[e] * 128;
        arow[r] = agg + (size_t)dstI[e] * 128;
    }

    // ---- direct A-fragment loads: lane's edge row = e_base + m0 + l15 ----
    int ar = e_base + m0 + l15;
    if (ar >= E) ar = E - 1;
    const float* rp = attr + (size_t)ar * 50;
    v8hf a0, a1;
    {
        const float2 q0 = *(const float2*)(rp + quad * 8 + 0);
        const float2 q1 = *(const float2*)(rp + quad * 8 + 2);
        const float2 q2 = *(const float2*)(rp + quad * 8 + 4);
        const float2 q3 = *(const float2*)(rp + quad * 8 + 6);
        v8hf t = {(_Float16)q0.x, (_Float16)q0.y, (_Float16)q1.x, (_Float16)q1.y,
                  (_Float16)q2.x, (_Float16)q2.y, (_Float16)q3.x, (_Float16)q3.y};
        a0 = t;
    }
    {
        const int cb = 32 + quad * 8;
        float2 q[4];
        #pragma unroll
        for (int j = 0; j < 4; ++j) {
            const int c = cb + 2 * j;       // even -> pairs never straddle 50
            if (c < 50) q[j] = *(const float2*)(rp + c);
            else        { q[j].x = 0.f; q[j].y = 0.f; }
        }
        v8hf t = {(_Float16)q[0].x, (_Float16)q[0].y, (_Float16)q[1].x, (_Float16)q[1].y,
                  (_Float16)q[2].x, (_Float16)q[2].y, (_Float16)q[3].x, (_Float16)q[3].y};
        a1 = t;
    }

    // ---- h-gather prefetch: latency hides behind both MFMA stages ----
    float hv[8][4];
    #pragma unroll
    for (int nt = 0; nt < 8; ++nt)
        #pragma unroll
        for (int r = 0; r < 4; ++r)
            hv[nt][r] = hrow[r][nt * 16 + l15];

    // ---- stage 1: u = ssp(attr @ W1^T + b1) -> Uh (wave-private rows) ----
    #pragma unroll
    for (int nt = 0; nt < 8; ++nt) {
        v4f acc = {0.f, 0.f, 0.f, 0.f};
        const v8hf bA = *(const v8hf*)&w1f[((nt * 2 + 0) * 64 + lane) * 8];
        const v8hf bB = *(const v8hf*)&w1f[((nt * 2 + 1) * 64 + lane) * 8];
        acc = __builtin_amdgcn_mfma_f32_16x16x32_f16(a0, bA, acc, 0, 0, 0);
        acc = __builtin_amdgcn_mfma_f32_16x16x32_f16(a1, bB, acc, 0, 0, 0);
        const float bj = b1[nt * 16 + l15];
        #pragma unroll
        for (int r = 0; r < 4; ++r)
            Uh[(m0 + quad * 4 + r) * 138 + nt * 16 + l15] =
                (_Float16)ssp_fast(acc[r] + bj);
    }

    // ---- stage 2 + D-layout epilogue (wave-private LDS rows, no barrier) ----
    v8hf ua[4];
    #pragma unroll
    for (int ks = 0; ks < 4; ++ks)
        ua[ks] = *(const v8hf*)&Uh[(m0 + l15) * 138 + ks * 32 + quad * 8];

    #pragma unroll
    for (int nt = 0; nt < 8; ++nt) {
        v4f acc = {0.f, 0.f, 0.f, 0.f};
        #pragma unroll
        for (int ks = 0; ks < 4; ++ks) {
            const v8hf b = *(const v8hf*)&w2f[((nt * 4 + ks) * 64 + lane) * 8];
            acc = __builtin_amdgcn_mfma_f32_16x16x32_f16(ua[ks], b, acc, 0, 0, 0);
        }
        const int col = nt * 16 + l15;
        const float bj = b2[col];
        #pragma unroll
        for (int r = 0; r < 4; ++r) {
            if (val[r]) {
                float wf = (acc[r] + bj) * cC[r];
                atomicAdd(&arow[r][col], wf * hv[nt][r]);
            }
        }
    }
}

extern "C" void kernel_launch(void* const* d_in, const int* in_sizes, int n_in,
                              void* d_out, int out_size, void* d_ws, size_t ws_size,
                              hipStream_t stream)
{
    const float* x   = (const float*)d_in[0];
    const int*   ei  = (const int*)  d_in[1];
    const float* ew  = (const float*)d_in[2];
    const float* ea  = (const float*)d_in[3];
    const float* w1  = (const float*)d_in[4];
    const float* b1  = (const float*)d_in[5];
    const float* w2  = (const float*)d_in[6];
    const float* b2  = (const float*)d_in[7];
    const float* l1w = (const float*)d_in[8];
    const float* l2w = (const float*)d_in[9];
    const float* l2b = (const float*)d_in[10];
    const float* lw  = (const float*)d_in[11];
    const float* lb  = (const float*)d_in[12];

    const int N = in_sizes[0] / 128;   // 40000
    const int E = in_sizes[2];         // 640000

    float* hbuf = (float*)d_ws;                           // N*128 f32
    float* agg  = hbuf + (size_t)N * 128;                 // N*128 f32
    _Float16* w1f = (_Float16*)(agg + (size_t)N * 128);   // 8192
    _Float16* w2f = w1f + 8192;
    _Float16* l1f = w2f + 16384;
    _Float16* l2f = l1f + 16384;
    _Float16* lwf = l2f + 16384;

    const int nb = (N + 63) / 64;
    const int eb = (E + 63) / 64;

    prep_kernel<<<288, 256, 0, stream>>>(w1, w2, l1w, l2w, lw,
                                         w1f, w2f, l1f, l2f, lwf);
    hipMemsetAsync(agg, 0, (size_t)N * 128 * sizeof(float), stream);
    h_gemm_kernel<<<dim3(nb, 2), 256, 0, stream>>>(x, l1f, hbuf, N);
    edge_kernel<<<eb, 256, 0, stream>>>(ea, ew, ei, ei + E, w1f, w2f, b1, b2,
                                        hbuf, agg, E);
    fused_out_kernel<<<dim3(nb, 2), 256, 0, stream>>>(agg, l2f, l2b, lwf, lb,
                                                      (float*)d_out, N);
}